// Round 5
// baseline (1673.446 us; speedup 1.0000x reference)
//
#include <hip/hip_runtime.h>
#include <math.h>

typedef _Float16 hfrag  __attribute__((ext_vector_type(8)));  // 8 f16 = 4 VGPR (MFMA A/B)
typedef _Float16 hpack  __attribute__((ext_vector_type(4)));  // 4 f16 = 8B packed store
typedef __fp16   pkv2   __attribute__((ext_vector_type(2)));  // cvt_pkrtz return type
typedef float    accf   __attribute__((ext_vector_type(16))); // MFMA C/D

constexpr float cTB = 6.0f;
constexpr float cMB = 0.001f;
constexpr float cMD = 0.001f;

constexpr int SH = 136;   // act buffer stride (halves): 16B-aligned rows, bank-balanced b128
constexpr int SE = 72;    // emb buffer stride (halves)
constexpr int SP = 100;   // p buffer stride (halves)

__device__ __forceinline__ float eluf(float x)  { return x > 0.f ? x : __expf(x) - 1.f; }
__device__ __forceinline__ float sigmf(float x) { return 1.f / (1.f + __expf(-x)); }
__device__ __forceinline__ float softplusf_(float x) { return x > 20.f ? x : log1pf(__expf(x)); }

// pack 4 f32 -> 4 f16 via v_cvt_pk_rtz_f16_f32 (2 instrs instead of 4 cvt + 2 pack)
__device__ __forceinline__ hpack pk4(float a, float b, float c, float d) {
  pkv2 lo = __builtin_amdgcn_cvt_pkrtz(a, b);
  pkv2 hi = __builtin_amdgcn_cvt_pkrtz(c, d);
  hpack r;
  r[0] = (_Float16)lo[0]; r[1] = (_Float16)lo[1];
  r[2] = (_Float16)hi[0]; r[3] = (_Float16)hi[1];
  return r;
}

// ---------------- weight prep: fp32 [n][K][F] -> f16 [n][Fpad][K] ----------------
__global__ void prep_transpose(const float* __restrict__ src, _Float16* __restrict__ dst,
                               int K, int F, int Fpad, int total) {
  int idx = blockIdx.x * 256 + threadIdx.x;
  if (idx >= total) return;
  int k = idx % K;
  int f = (idx / K) % Fpad;
  int n = idx / (K * Fpad);
  float v = (f < F) ? src[(size_t)n * K * F + (size_t)k * F + f] : 0.f;
  dst[idx] = (_Float16)v;
}

// GEMM: D[f][m] += W^T[f][k] * Act^T[k][m].  A row = f0+col (global f16, [f][K]),
// B col = mt+col (LDS [m][k]).  Single n-tile per wave.
#define GEMM1(WROW, BPTR, BSTRIDE, KDIM, A0)                                   \
  _Pragma("unroll")                                                            \
  for (int c = 0; c < (KDIM); c += 16) {                                       \
    hfrag av = *(const hfrag*)((WROW) + c + q8);                               \
    hfrag bv = *(const hfrag*)((BPTR) + (mt + col) * (BSTRIDE) + c + q8);      \
    A0 = __builtin_amdgcn_mfma_f32_32x32x16_f16(av, bv, A0, 0, 0, 0);          \
  }

__global__ __launch_bounds__(512, 6) void nsf_mfma(
    const float* __restrict__ gy,   const float* __restrict__ gctx,
    const float* __restrict__ eW1,  const float* __restrict__ eb1,
    const float* __restrict__ eb2,  const float* __restrict__ eb3,
    const float* __restrict__ gib,  const float* __restrict__ gcb,
    const float* __restrict__ bb1,  const float* __restrict__ bb2,
    const float* __restrict__ bbc,  const float* __restrict__ gob,
    const _Float16* __restrict__ wE2T, const _Float16* __restrict__ wE3T,
    const _Float16* __restrict__ wCtxT, const _Float16* __restrict__ wW1T,
    const _Float16* __restrict__ wW2T,  const _Float16* __restrict__ wWcT,
    const _Float16* __restrict__ wOutT, float* __restrict__ gout)
{
  __shared__ _Float16 sH[64 * SH];   // act buffer (elu(h) / raw h), [m][k]
  __shared__ _Float16 sT[64 * SH];   // act buffer (elu(t1)); aliased as p-buffer [m][SP]
  __shared__ _Float16 sE[64 * SE];   // embedding [m][k]

  const int tid  = threadIdx.x;
  const int wid  = tid >> 6;      // wave 0..7
  const int lane = tid & 63;
  const int col  = lane & 31;     // MFMA col
  const int q8   = (lane >> 5) * 8;
  const int q4   = (lane >> 5) * 4;
  const int ft   = wid & 3;       // f-slice 0..3
  const int nt   = wid >> 2;      // n-tile 0..1
  const int f0   = ft * 32;
  const int mt   = nt * 32;
  const int mrow = mt + col;
  const int m0   = blockIdx.x * 64;

  // ---------------- embedding ----------------
  {  // stage 1: fp32, 8 e-groups x 64 m
    const int m  = tid & 63;
    const int eg = tid >> 6;
    const float2 c2 = *(const float2*)&gctx[(size_t)(m0 + m) * 2];
    #pragma unroll
    for (int j = 0; j < 8; ++j) {
      const int e = eg * 8 + j;
      sH[m * SE + e] = (_Float16)eluf(c2.x * eW1[e] + c2.y * eW1[64 + e] + eb1[e]);
    }
  }
  __syncthreads();
  if (wid < 4) {  // stage 2: MFMA, waves 0-3, one (ft2, nt2) tile each
    const int ft2 = wid & 1, nt2 = wid >> 1;
    accf a = {};
    const _Float16* wr = wE2T + (32 * ft2 + col) * 64;
    #pragma unroll
    for (int c = 0; c < 64; c += 16) {
      hfrag av = *(const hfrag*)(wr + c + q8);
      hfrag bv = *(const hfrag*)(&sH[(nt2 * 32 + col) * SE + c + q8]);
      a = __builtin_amdgcn_mfma_f32_32x32x16_f16(av, bv, a, 0, 0, 0);
    }
    const int mr2 = nt2 * 32 + col;
    #pragma unroll
    for (int g = 0; g < 4; ++g) {
      const int e = 32 * ft2 + 8 * g + q4;
      const float4 b = *(const float4*)&eb2[e];
      *(hpack*)&sT[mr2 * SE + e] =
          pk4(eluf(a[4 * g + 0] + b.x), eluf(a[4 * g + 1] + b.y),
              eluf(a[4 * g + 2] + b.z), eluf(a[4 * g + 3] + b.w));
    }
  }
  __syncthreads();
  if (wid < 4) {  // stage 3: MFMA -> sE
    const int ft2 = wid & 1, nt2 = wid >> 1;
    accf a = {};
    const _Float16* wr = wE3T + (32 * ft2 + col) * 64;
    #pragma unroll
    for (int c = 0; c < 64; c += 16) {
      hfrag av = *(const hfrag*)(wr + c + q8);
      hfrag bv = *(const hfrag*)(&sT[(nt2 * 32 + col) * SE + c + q8]);
      a = __builtin_amdgcn_mfma_f32_32x32x16_f16(av, bv, a, 0, 0, 0);
    }
    const int mr2 = nt2 * 32 + col;
    #pragma unroll
    for (int g = 0; g < 4; ++g) {
      const int e = 32 * ft2 + 8 * g + q4;
      const float4 b = *(const float4*)&eb3[e];
      *(hpack*)&sE[mr2 * SE + e] =
          pk4(eluf(a[4 * g + 0] + b.x), eluf(a[4 * g + 1] + b.y),
              eluf(a[4 * g + 2] + b.z), eluf(a[4 * g + 3] + b.w));
    }
  }
  __syncthreads();

  // ---------------- flow layers ----------------
  float z = 0.f, lad = 0.f;
  if (wid == 7) z = gy[m0 + lane];   // wave 7 owns the spline (idle in out-GEMM)

  accf h;  // raw h (fp32) for this wave's (f-slice, n-tile)

  for (int l = 0; l < 6; ++l) {
    // ---- ctx: h = init_b + ctx_b + emb @ ctx_W ----
    {
      accf a = {};
      const _Float16* wr = wCtxT + (size_t)l * 8192 + (f0 + col) * 64;
      GEMM1(wr, sE, SE, 64, a)
      #pragma unroll
      for (int g = 0; g < 4; ++g) {
        const int f = f0 + 8 * g + q4;
        const float4 bi = *(const float4*)&gib[l * 128 + f];
        const float4 bc = *(const float4*)&gcb[l * 128 + f];
        #pragma unroll
        for (int r = 0; r < 4; ++r)
          h[4 * g + r] = a[4 * g + r] + (&bi.x)[r] + (&bc.x)[r];
        *(hpack*)&sH[mrow * SH + f] =
            pk4(eluf(h[4 * g + 0]), eluf(h[4 * g + 1]),
                eluf(h[4 * g + 2]), eluf(h[4 * g + 3]));
      }
    }
    __syncthreads();

    // ---- residual blocks ----
    for (int jb = 0; jb < 2; ++jb) {
      const int wi = l * 2 + jb;
      {  // t1 = elu(elu(h) @ W1 + b1) -> sT
        accf a = {};
        const _Float16* wr = wW1T + (size_t)wi * 16384 + (f0 + col) * 128;
        GEMM1(wr, sH, SH, 128, a)
        #pragma unroll
        for (int g = 0; g < 4; ++g) {
          const int f = f0 + 8 * g + q4;
          const float4 bv = *(const float4*)&bb1[wi * 128 + f];
          *(hpack*)&sT[mrow * SH + f] =
              pk4(eluf(a[4 * g + 0] + bv.x), eluf(a[4 * g + 1] + bv.y),
                  eluf(a[4 * g + 2] + bv.z), eluf(a[4 * g + 3] + bv.w));
        }
      }
      __syncthreads();
      {  // t2 = elu(t1)@W2 + b2 ; gate = sigmoid(emb@Wc + bc); h += t2*gate
        accf a2 = {}, ag = {};
        const _Float16* wr2 = wW2T + (size_t)wi * 16384 + (f0 + col) * 128;
        GEMM1(wr2, sT, SH, 128, a2)
        const _Float16* wrc = wWcT + (size_t)wi * 8192 + (f0 + col) * 64;
        GEMM1(wrc, sE, SE, 64, ag)
        const bool last = (jb == 1);
        #pragma unroll
        for (int g = 0; g < 4; ++g) {
          const int f = f0 + 8 * g + q4;
          const float4 b2v = *(const float4*)&bb2[wi * 128 + f];
          const float4 bcv = *(const float4*)&bbc[wi * 128 + f];
          float s[4];
          #pragma unroll
          for (int r = 0; r < 4; ++r) {
            const float gate = sigmf(ag[4 * g + r] + (&bcv.x)[r]);
            const float hv = h[4 * g + r] + (a2[4 * g + r] + (&b2v.x)[r]) * gate;
            h[4 * g + r] = hv;
            s[r] = last ? hv : eluf(hv);   // last block: stage RAW h for out-GEMM
          }
          *(hpack*)&sH[mrow * SH + f] = pk4(s[0], s[1], s[2], s[3]);
        }
      }
      __syncthreads();
    }

    // ---- p = h @ out_W + out_b  (waves with ft<3: F=96 incl. 1 zero pad row) ----
    if (ft < 3) {
      accf a = {};
      const _Float16* wr = wOutT + (size_t)l * 12288 + (f0 + col) * 128;
      GEMM1(wr, sH, SH, 128, a)
      #pragma unroll
      for (int g = 0; g < 4; ++g) {
        const int f = f0 + 8 * g + q4;
        float s[4];
        #pragma unroll
        for (int r = 0; r < 4; ++r) {
          const float ob = (f + r < 95) ? gob[l * 95 + f + r] : 0.f;
          s[r] = a[4 * g + r] + ob;
        }
        *(hpack*)&sT[mrow * SP + f] = pk4(s[0], s[1], s[2], s[3]);
      }
    }
    __syncthreads();

    // ---- rational-quadratic spline: wave 7, one lane per sample ----
    // (overlaps with waves 0-6 running next layer's ctx-GEMM; t1's sT write
    //  is behind the post-ctx barrier which wave 7 reaches only after this)
    if (wid == 7) {
      const float invS = 0.08838834764831845f;  // 1/sqrt(128)
      const _Float16* pmv = &sT[lane * SP];
      auto pm = [&](int i) -> float { return (float)pmv[i]; };
      float mw = pm(0), mh = pm(32);
      #pragma unroll
      for (int i = 1; i < 32; ++i) {
        mw = fmaxf(mw, pm(i));
        mh = fmaxf(mh, pm(32 + i));
      }
      float sw = 0.f, sh = 0.f;
      #pragma unroll
      for (int i = 0; i < 32; ++i) {
        sw += __expf((pm(i) - mw) * invS);
        sh += __expf((pm(32 + i) - mh) * invS);
      }
      const float cw_scale = (1.0f - cMB * 32.f) / sw;
      const float ch_scale = (1.0f - cMB * 32.f) / sh;
      const float yc = fminf(fmaxf(z, -cTB), cTB);

      int idx = 0;
      float cum = 0.f, cw_k = -cTB, cw_k1 = cTB;
      bool take = true;
      #pragma unroll
      for (int i = 1; i <= 32; ++i) {
        float cwi;
        if (i < 32) {
          cum += cMB + __expf((pm(i - 1) - mw) * invS) * cw_scale;
          cwi = 2.f * cTB * cum - cTB;
        } else {
          cwi = cTB;
        }
        if (take) { cw_k1 = cwi; take = false; }
        if (i < 32 && yc >= cwi) { idx = i; cw_k = cwi; take = true; }
      }

      cum = 0.f;
      float ch_k = -cTB, ch_k1 = cTB;
      #pragma unroll
      for (int i = 1; i < 32; ++i) {
        cum += cMB + __expf((pm(32 + i - 1) - mh) * invS) * ch_scale;
        const float chi = 2.f * cTB * cum - cTB;
        if (i == idx) ch_k = chi;
        if (i == idx + 1) ch_k1 = chi;
      }

      const float w_k = cw_k1 - cw_k;
      const float h_k = ch_k1 - ch_k;
      const float d_k  = (idx == 0)  ? 1.f : cMD + softplusf_(pm(64 + idx - 1));
      const float d_k1 = (idx == 31) ? 1.f : cMD + softplusf_(pm(64 + idx));

      const float s_k  = h_k / w_k;
      const float th   = (yc - cw_k) / w_k;
      const float th1m = th * (1.f - th);
      const float numv = h_k * (s_k * th * th + d_k * th1m);
      const float denv = s_k + (d_k + d_k1 - 2.f * s_k) * th1m;
      const float outv = ch_k + numv / denv;
      const float omt  = 1.f - th;
      const float dnum = s_k * s_k * (d_k1 * th * th + 2.f * s_k * th1m + d_k * omt * omt);
      const float ladv = __logf(dnum) - 2.f * __logf(denv);
      const bool inside = (z >= -cTB) && (z <= cTB);
      if (inside) { z = outv; lad += ladv; }
    }
  }

  if (wid == 7) {
    gout[m0 + lane] = -0.5f * z * z - 0.9189385332046727f + lad;
  }
}

extern "C" void kernel_launch(void* const* d_in, const int* in_sizes, int n_in,
                              void* d_out, int out_size, void* d_ws, size_t ws_size,
                              hipStream_t stream) {
  const float* gy   = (const float*)d_in[0];
  const float* gctx = (const float*)d_in[1];
  const float* eW1  = (const float*)d_in[2];
  const float* eb1  = (const float*)d_in[3];
  const float* eW2  = (const float*)d_in[4];
  const float* eb2  = (const float*)d_in[5];
  const float* eW3  = (const float*)d_in[6];
  const float* eb3  = (const float*)d_in[7];
  const float* gib  = (const float*)d_in[8];
  const float* gcW  = (const float*)d_in[9];
  const float* gcb  = (const float*)d_in[10];
  const float* bW1  = (const float*)d_in[11];
  const float* bb1  = (const float*)d_in[12];
  const float* bW2  = (const float*)d_in[13];
  const float* bb2  = (const float*)d_in[14];
  const float* bWc  = (const float*)d_in[15];
  const float* bbc  = (const float*)d_in[16];
  const float* goW  = (const float*)d_in[17];
  const float* gob  = (const float*)d_in[18];

  _Float16* ws    = (_Float16*)d_ws;
  _Float16* wE2T  = ws;                  // 64*64
  _Float16* wE3T  = wE2T + 4096;         // 64*64
  _Float16* wCtxT = wE3T + 4096;         // 6*128*64
  _Float16* wW1T  = wCtxT + 49152;       // 12*128*128
  _Float16* wW2T  = wW1T + 196608;       // 12*128*128
  _Float16* wWcT  = wW2T + 196608;       // 12*128*64
  _Float16* wOutT = wWcT + 98304;        // 6*96*128

  auto prep = [&](const float* s, _Float16* d, int K, int F, int Fp, int n) {
    int tot = n * Fp * K;
    prep_transpose<<<(tot + 255) / 256, 256, 0, stream>>>(s, d, K, F, Fp, tot);
  };
  prep(eW2, wE2T, 64, 64, 64, 1);
  prep(eW3, wE3T, 64, 64, 64, 1);
  prep(gcW, wCtxT, 64, 128, 128, 6);
  prep(bW1, wW1T, 128, 128, 128, 12);
  prep(bW2, wW2T, 128, 128, 128, 12);
  prep(bWc, wWcT, 64, 128, 128, 12);
  prep(goW, wOutT, 128, 95, 96, 6);

  nsf_mfma<<<dim3(262144 / 64), dim3(512), 0, stream>>>(
      gy, gctx, eW1, eb1, eb2, eb3, gib, gcb, bb1, bb2, bbc, gob,
      wE2T, wE3T, wCtxT, wW1T, wW2T, wWcT, wOutT, (float*)d_out);
}

// Round 6
// 1619.779 us; speedup vs baseline: 1.0331x; 1.0331x over previous
//
#include <hip/hip_runtime.h>
#include <math.h>

typedef _Float16 hfrag  __attribute__((ext_vector_type(8)));  // 8 f16 = 4 VGPR (MFMA A/B)
typedef _Float16 hpack  __attribute__((ext_vector_type(4)));  // 4 f16 = 8B packed store
typedef __fp16   pkv2   __attribute__((ext_vector_type(2)));  // cvt_pkrtz return type
typedef float    accf   __attribute__((ext_vector_type(16))); // MFMA C/D

constexpr float cTB = 6.0f;
constexpr float cMB = 0.001f;
constexpr float cMD = 0.001f;

constexpr int SH = 136;   // act buffer stride (halves): 16B-aligned rows, bank-balanced b128
constexpr int SE = 72;    // emb buffer stride (halves)
constexpr int SP = 100;   // p buffer stride (halves)

__device__ __forceinline__ float eluf(float x)  { return x > 0.f ? x : __expf(x) - 1.f; }
__device__ __forceinline__ float sigmf(float x) { return 1.f / (1.f + __expf(-x)); }
__device__ __forceinline__ float softplusf_(float x) { return x > 20.f ? x : log1pf(__expf(x)); }

// pack 4 f32 -> 4 f16 via v_cvt_pk_rtz_f16_f32 (2 instrs instead of 4 cvt + 2 pack)
__device__ __forceinline__ hpack pk4(float a, float b, float c, float d) {
  pkv2 lo = __builtin_amdgcn_cvt_pkrtz(a, b);
  pkv2 hi = __builtin_amdgcn_cvt_pkrtz(c, d);
  hpack r;
  r[0] = (_Float16)lo[0]; r[1] = (_Float16)lo[1];
  r[2] = (_Float16)hi[0]; r[3] = (_Float16)hi[1];
  return r;
}

// ---------------- weight prep: fp32 [n][K][F] -> f16 [n][Fpad][K] ----------------
__global__ void prep_transpose(const float* __restrict__ src, _Float16* __restrict__ dst,
                               int K, int F, int Fpad, int total) {
  int idx = blockIdx.x * 256 + threadIdx.x;
  if (idx >= total) return;
  int k = idx % K;
  int f = (idx / K) % Fpad;
  int n = idx / (K * Fpad);
  float v = (f < F) ? src[(size_t)n * K * F + (size_t)k * F + f] : 0.f;
  dst[idx] = (_Float16)v;
}

// GEMM: D[f][m] += W^T[f][k] * Act^T[k][m].  A row = f0+col (global f16, [f][K]),
// B col = mt+col (LDS [m][k]).  Single n-tile per wave.
#define GEMM1(WROW, BPTR, BSTRIDE, KDIM, A0)                                   \
  _Pragma("unroll")                                                            \
  for (int c = 0; c < (KDIM); c += 16) {                                       \
    hfrag av = *(const hfrag*)((WROW) + c + q8);                               \
    hfrag bv = *(const hfrag*)((BPTR) + (mt + col) * (BSTRIDE) + c + q8);      \
    A0 = __builtin_amdgcn_mfma_f32_32x32x16_f16(av, bv, A0, 0, 0, 0);          \
  }

__global__ __launch_bounds__(512, 4) void nsf_mfma(
    const float* __restrict__ gy,   const float* __restrict__ gctx,
    const float* __restrict__ eW1,  const float* __restrict__ eb1,
    const float* __restrict__ eb2,  const float* __restrict__ eb3,
    const float* __restrict__ gib,  const float* __restrict__ gcb,
    const float* __restrict__ bb1,  const float* __restrict__ bb2,
    const float* __restrict__ bbc,  const float* __restrict__ gob,
    const _Float16* __restrict__ wE2T, const _Float16* __restrict__ wE3T,
    const _Float16* __restrict__ wCtxT, const _Float16* __restrict__ wW1T,
    const _Float16* __restrict__ wW2T,  const _Float16* __restrict__ wWcT,
    const _Float16* __restrict__ wOutT, float* __restrict__ gout)
{
  __shared__ _Float16 sH[64 * SH];   // act buffer (elu(h) / raw h), [m][k]
  __shared__ _Float16 sT[64 * SH];   // act buffer (elu(t1)); aliased as p-buffer [m][SP]
  __shared__ _Float16 sE[64 * SE];   // embedding [m][k]

  const int tid  = threadIdx.x;
  const int wid  = tid >> 6;      // wave 0..7
  const int lane = tid & 63;
  const int col  = lane & 31;     // MFMA col
  const int q8   = (lane >> 5) * 8;
  const int q4   = (lane >> 5) * 4;
  const int ft   = wid & 3;       // f-slice 0..3
  const int nt   = wid >> 2;      // n-tile 0..1
  const int f0   = ft * 32;
  const int mt   = nt * 32;
  const int mrow = mt + col;
  const int m0   = blockIdx.x * 64;

  // ---------------- embedding ----------------
  {  // stage 1: fp32, 8 e-groups x 64 m
    const int m  = tid & 63;
    const int eg = tid >> 6;
    const float2 c2 = *(const float2*)&gctx[(size_t)(m0 + m) * 2];
    #pragma unroll
    for (int j = 0; j < 8; ++j) {
      const int e = eg * 8 + j;
      sH[m * SE + e] = (_Float16)eluf(c2.x * eW1[e] + c2.y * eW1[64 + e] + eb1[e]);
    }
  }
  __syncthreads();
  if (wid < 4) {  // stage 2: MFMA, waves 0-3, one (ft2, nt2) tile each
    const int ft2 = wid & 1, nt2 = wid >> 1;
    accf a = {};
    const _Float16* wr = wE2T + (32 * ft2 + col) * 64;
    #pragma unroll
    for (int c = 0; c < 64; c += 16) {
      hfrag av = *(const hfrag*)(wr + c + q8);
      hfrag bv = *(const hfrag*)(&sH[(nt2 * 32 + col) * SE + c + q8]);
      a = __builtin_amdgcn_mfma_f32_32x32x16_f16(av, bv, a, 0, 0, 0);
    }
    const int mr2 = nt2 * 32 + col;
    #pragma unroll
    for (int g = 0; g < 4; ++g) {
      const int e = 32 * ft2 + 8 * g + q4;
      const float4 b = *(const float4*)&eb2[e];
      *(hpack*)&sT[mr2 * SE + e] =
          pk4(eluf(a[4 * g + 0] + b.x), eluf(a[4 * g + 1] + b.y),
              eluf(a[4 * g + 2] + b.z), eluf(a[4 * g + 3] + b.w));
    }
  }
  __syncthreads();
  if (wid < 4) {  // stage 3: MFMA -> sE
    const int ft2 = wid & 1, nt2 = wid >> 1;
    accf a = {};
    const _Float16* wr = wE3T + (32 * ft2 + col) * 64;
    #pragma unroll
    for (int c = 0; c < 64; c += 16) {
      hfrag av = *(const hfrag*)(wr + c + q8);
      hfrag bv = *(const hfrag*)(&sT[(nt2 * 32 + col) * SE + c + q8]);
      a = __builtin_amdgcn_mfma_f32_32x32x16_f16(av, bv, a, 0, 0, 0);
    }
    const int mr2 = nt2 * 32 + col;
    #pragma unroll
    for (int g = 0; g < 4; ++g) {
      const int e = 32 * ft2 + 8 * g + q4;
      const float4 b = *(const float4*)&eb3[e];
      *(hpack*)&sE[mr2 * SE + e] =
          pk4(eluf(a[4 * g + 0] + b.x), eluf(a[4 * g + 1] + b.y),
              eluf(a[4 * g + 2] + b.z), eluf(a[4 * g + 3] + b.w));
    }
  }
  __syncthreads();

  // ---------------- flow layers ----------------
  float z = 0.f, lad = 0.f;
  if (wid == 7) z = gy[m0 + lane];   // wave 7 owns the spline (idle in out-GEMM)

  accf h;  // raw h (fp32) for this wave's (f-slice, n-tile)

  for (int l = 0; l < 6; ++l) {
    // ---- ctx: h = init_b + ctx_b + emb @ ctx_W ----
    {
      accf a = {};
      const _Float16* wr = wCtxT + (size_t)l * 8192 + (f0 + col) * 64;
      GEMM1(wr, sE, SE, 64, a)
      #pragma unroll
      for (int g = 0; g < 4; ++g) {
        const int f = f0 + 8 * g + q4;
        const float4 bi = *(const float4*)&gib[l * 128 + f];
        const float4 bc = *(const float4*)&gcb[l * 128 + f];
        #pragma unroll
        for (int r = 0; r < 4; ++r)
          h[4 * g + r] = a[4 * g + r] + (&bi.x)[r] + (&bc.x)[r];
        *(hpack*)&sH[mrow * SH + f] =
            pk4(eluf(h[4 * g + 0]), eluf(h[4 * g + 1]),
                eluf(h[4 * g + 2]), eluf(h[4 * g + 3]));
      }
    }
    __syncthreads();

    // ---- residual blocks ----
    for (int jb = 0; jb < 2; ++jb) {
      const int wi = l * 2 + jb;
      {  // t1 = elu(elu(h) @ W1 + b1) -> sT
        accf a = {};
        const _Float16* wr = wW1T + (size_t)wi * 16384 + (f0 + col) * 128;
        GEMM1(wr, sH, SH, 128, a)
        #pragma unroll
        for (int g = 0; g < 4; ++g) {
          const int f = f0 + 8 * g + q4;
          const float4 bv = *(const float4*)&bb1[wi * 128 + f];
          *(hpack*)&sT[mrow * SH + f] =
              pk4(eluf(a[4 * g + 0] + bv.x), eluf(a[4 * g + 1] + bv.y),
                  eluf(a[4 * g + 2] + bv.z), eluf(a[4 * g + 3] + bv.w));
        }
      }
      __syncthreads();
      {  // t2 = elu(t1)@W2 + b2 ; gate = sigmoid(emb@Wc + bc); h += t2*gate
        accf a2 = {}, ag = {};
        const _Float16* wr2 = wW2T + (size_t)wi * 16384 + (f0 + col) * 128;
        GEMM1(wr2, sT, SH, 128, a2)
        const _Float16* wrc = wWcT + (size_t)wi * 8192 + (f0 + col) * 64;
        GEMM1(wrc, sE, SE, 64, ag)
        const bool last = (jb == 1);
        #pragma unroll
        for (int g = 0; g < 4; ++g) {
          const int f = f0 + 8 * g + q4;
          const float4 b2v = *(const float4*)&bb2[wi * 128 + f];
          const float4 bcv = *(const float4*)&bbc[wi * 128 + f];
          float s[4];
          #pragma unroll
          for (int r = 0; r < 4; ++r) {
            const float gate = sigmf(ag[4 * g + r] + (&bcv.x)[r]);
            const float hv = h[4 * g + r] + (a2[4 * g + r] + (&b2v.x)[r]) * gate;
            h[4 * g + r] = hv;
            s[r] = last ? hv : eluf(hv);   // last block: stage RAW h for out-GEMM
          }
          *(hpack*)&sH[mrow * SH + f] = pk4(s[0], s[1], s[2], s[3]);
        }
      }
      __syncthreads();
    }

    // ---- p = h @ out_W + out_b  (waves with ft<3: F=96 incl. 1 zero pad row) ----
    if (ft < 3) {
      accf a = {};
      const _Float16* wr = wOutT + (size_t)l * 12288 + (f0 + col) * 128;
      GEMM1(wr, sH, SH, 128, a)
      #pragma unroll
      for (int g = 0; g < 4; ++g) {
        const int f = f0 + 8 * g + q4;
        float s[4];
        #pragma unroll
        for (int r = 0; r < 4; ++r) {
          const float ob = (f + r < 95) ? gob[l * 95 + f + r] : 0.f;
          s[r] = a[4 * g + r] + ob;
        }
        *(hpack*)&sT[mrow * SP + f] = pk4(s[0], s[1], s[2], s[3]);
      }
    }
    __syncthreads();

    // ---- rational-quadratic spline: wave 7, one lane per sample ----
    // (overlaps with waves 0-6 running next layer's ctx-GEMM; t1's sT write
    //  is behind the post-ctx barrier which wave 7 reaches only after this)
    if (wid == 7) {
      const float invS = 0.08838834764831845f;  // 1/sqrt(128)
      const _Float16* pmv = &sT[lane * SP];
      auto pm = [&](int i) -> float { return (float)pmv[i]; };
      float mw = pm(0), mh = pm(32);
      #pragma unroll
      for (int i = 1; i < 32; ++i) {
        mw = fmaxf(mw, pm(i));
        mh = fmaxf(mh, pm(32 + i));
      }
      float sw = 0.f, sh = 0.f;
      #pragma unroll
      for (int i = 0; i < 32; ++i) {
        sw += __expf((pm(i) - mw) * invS);
        sh += __expf((pm(32 + i) - mh) * invS);
      }
      const float cw_scale = (1.0f - cMB * 32.f) / sw;
      const float ch_scale = (1.0f - cMB * 32.f) / sh;
      const float yc = fminf(fmaxf(z, -cTB), cTB);

      int idx = 0;
      float cum = 0.f, cw_k = -cTB, cw_k1 = cTB;
      bool take = true;
      #pragma unroll
      for (int i = 1; i <= 32; ++i) {
        float cwi;
        if (i < 32) {
          cum += cMB + __expf((pm(i - 1) - mw) * invS) * cw_scale;
          cwi = 2.f * cTB * cum - cTB;
        } else {
          cwi = cTB;
        }
        if (take) { cw_k1 = cwi; take = false; }
        if (i < 32 && yc >= cwi) { idx = i; cw_k = cwi; take = true; }
      }

      cum = 0.f;
      float ch_k = -cTB, ch_k1 = cTB;
      #pragma unroll
      for (int i = 1; i < 32; ++i) {
        cum += cMB + __expf((pm(32 + i - 1) - mh) * invS) * ch_scale;
        const float chi = 2.f * cTB * cum - cTB;
        if (i == idx) ch_k = chi;
        if (i == idx + 1) ch_k1 = chi;
      }

      const float w_k = cw_k1 - cw_k;
      const float h_k = ch_k1 - ch_k;
      const float d_k  = (idx == 0)  ? 1.f : cMD + softplusf_(pm(64 + idx - 1));
      const float d_k1 = (idx == 31) ? 1.f : cMD + softplusf_(pm(64 + idx));

      const float s_k  = h_k / w_k;
      const float th   = (yc - cw_k) / w_k;
      const float th1m = th * (1.f - th);
      const float numv = h_k * (s_k * th * th + d_k * th1m);
      const float denv = s_k + (d_k + d_k1 - 2.f * s_k) * th1m;
      const float outv = ch_k + numv / denv;
      const float omt  = 1.f - th;
      const float dnum = s_k * s_k * (d_k1 * th * th + 2.f * s_k * th1m + d_k * omt * omt);
      const float ladv = __logf(dnum) - 2.f * __logf(denv);
      const bool inside = (z >= -cTB) && (z <= cTB);
      if (inside) { z = outv; lad += ladv; }
    }
  }

  if (wid == 7) {
    gout[m0 + lane] = -0.5f * z * z - 0.9189385332046727f + lad;
  }
}

extern "C" void kernel_launch(void* const* d_in, const int* in_sizes, int n_in,
                              void* d_out, int out_size, void* d_ws, size_t ws_size,
                              hipStream_t stream) {
  const float* gy   = (const float*)d_in[0];
  const float* gctx = (const float*)d_in[1];
  const float* eW1  = (const float*)d_in[2];
  const float* eb1  = (const float*)d_in[3];
  const float* eW2  = (const float*)d_in[4];
  const float* eb2  = (const float*)d_in[5];
  const float* eW3  = (const float*)d_in[6];
  const float* eb3  = (const float*)d_in[7];
  const float* gib  = (const float*)d_in[8];
  const float* gcW  = (const float*)d_in[9];
  const float* gcb  = (const float*)d_in[10];
  const float* bW1  = (const float*)d_in[11];
  const float* bb1  = (const float*)d_in[12];
  const float* bW2  = (const float*)d_in[13];
  const float* bb2  = (const float*)d_in[14];
  const float* bWc  = (const float*)d_in[15];
  const float* bbc  = (const float*)d_in[16];
  const float* goW  = (const float*)d_in[17];
  const float* gob  = (const float*)d_in[18];

  _Float16* ws    = (_Float16*)d_ws;
  _Float16* wE2T  = ws;                  // 64*64
  _Float16* wE3T  = wE2T + 4096;         // 64*64
  _Float16* wCtxT = wE3T + 4096;         // 6*128*64
  _Float16* wW1T  = wCtxT + 49152;       // 12*128*128
  _Float16* wW2T  = wW1T + 196608;       // 12*128*128
  _Float16* wWcT  = wW2T + 196608;       // 12*128*64
  _Float16* wOutT = wWcT + 98304;        // 6*96*128

  auto prep = [&](const float* s, _Float16* d, int K, int F, int Fp, int n) {
    int tot = n * Fp * K;
    prep_transpose<<<(tot + 255) / 256, 256, 0, stream>>>(s, d, K, F, Fp, tot);
  };
  prep(eW2, wE2T, 64, 64, 64, 1);
  prep(eW3, wE3T, 64, 64, 64, 1);
  prep(gcW, wCtxT, 64, 128, 128, 6);
  prep(bW1, wW1T, 128, 128, 128, 12);
  prep(bW2, wW2T, 128, 128, 128, 12);
  prep(bWc, wWcT, 64, 128, 128, 12);
  prep(goW, wOutT, 128, 95, 96, 6);

  nsf_mfma<<<dim3(262144 / 64), dim3(512), 0, stream>>>(
      gy, gctx, eW1, eb1, eb2, eb3, gib, gcb, bb1, bb2, bbc, gob,
      wE2T, wE3T, wCtxT, wW1T, wW2T, wWcT, wOutT, (float*)d_out);
}